// Round 1
// baseline (948.852 us; speedup 1.0000x reference)
//
#include <hip/hip_runtime.h>
#include <hip/hip_bf16.h>
#include <math.h>

#define Bn   16
#define Jn   2048
#define Hn   2048
#define OUTn 128
#define HDn  16

#define TJ  64     // j-rows per block
#define KC  64     // k-chunk
#define NW  160    // padded N: 128 q + 16 v + 1 ksum + 15 dead
#define LDP 65     // LDS row stride in floats (65%32=1 -> conflict-free column reads)

// ---------------- prep: wksum[c] = sum_h wk_w[h,c]; ws[0] = sum_h wk_b[h] ----
__global__ __launch_bounds__(256) void prep_kernel(const float* __restrict__ wk_w,
                                                   const float* __restrict__ wk_b,
                                                   float* __restrict__ ws) {
  const int blk = blockIdx.x;
  const int tid = threadIdx.x;
  __shared__ float red[256];
  if (blk < 32) {
    // 64 c-values per block; 4 h-lanes per c
    const int cl = tid & 63;
    const int hl = tid >> 6;
    const int c  = blk * 64 + cl;
    float s = 0.f;
    for (int h = hl; h < Hn; h += 4) s += wk_w[(size_t)h * Hn + c];
    red[hl * 64 + cl] = s;
    __syncthreads();
    if (tid < 64)
      ws[8 + blk * 64 + tid] = red[tid] + red[64 + tid] + red[128 + tid] + red[192 + tid];
  } else {
    float s = 0.f;
    for (int h = tid; h < Hn; h += 256) s += wk_b[h];
    red[tid] = s;
    __syncthreads();
    for (int off = 128; off > 0; off >>= 1) {
      if (tid < off) red[tid] += red[tid + off];
      __syncthreads();
    }
    if (tid == 0) ws[0] = red[0];
  }
}

// ---------------- fused projection: qT[b,i,j], v[b,j,d], ksum[b,j] ----------
__global__ __launch_bounds__(256) void proj_kernel(
    const float* __restrict__ vec,
    const float* __restrict__ wq_w,
    const float* __restrict__ wq_b,
    const float* __restrict__ wv_w,
    const float* __restrict__ wv_b,
    const float* __restrict__ wsc,    // ws base: [0]=wkb_sum, [8..8+2048)=wksum
    float* __restrict__ qT,           // [B,128,J]
    float* __restrict__ ksum,         // [B,J]
    float* __restrict__ vout)         // [B,J,16]
{
  __shared__ float As[TJ * LDP];      // 16640 B
  __shared__ float Ws[NW * LDP];      // 41600 B
  const int tid = threadIdx.x;
  const int b   = blockIdx.x >> 5;    // / (Jn/TJ)
  const int jt  = blockIdx.x & 31;
  const int j0  = jt * TJ;
  const int tx  = tid & 15;           // n-group: cols tx*10 .. +9
  const int ty  = tid >> 4;           // m-group: rows ty*4 .. +3

  float acc[4][10];
#pragma unroll
  for (int mi = 0; mi < 4; ++mi)
#pragma unroll
    for (int ni = 0; ni < 10; ++ni) acc[mi][ni] = 0.f;

  const float* vecb = vec + (size_t)b * Jn * Hn;

  for (int k0 = 0; k0 < Hn; k0 += KC) {
    // stage A tile: TJ x KC  (coalesced float4 loads)
    for (int i = tid; i < TJ * (KC / 4); i += 256) {
      const int r  = i >> 4;
      const int kk = (i & 15) << 2;
      float4 t4 = *(const float4*)(vecb + (size_t)(j0 + r) * Hn + k0 + kk);
      float* dst = &As[r * LDP + kk];
      dst[0] = t4.x; dst[1] = t4.y; dst[2] = t4.z; dst[3] = t4.w;
    }
    // stage W tile: NW x KC
    for (int i = tid; i < NW * (KC / 4); i += 256) {
      const int n  = i >> 4;
      const int kk = (i & 15) << 2;
      float4 t4;
      if (n < 128)        t4 = *(const float4*)(wq_w + (size_t)n * Hn + k0 + kk);
      else if (n < 144)   t4 = *(const float4*)(wv_w + (size_t)(n - 128) * Hn + k0 + kk);
      else if (n == 144)  t4 = *(const float4*)(wsc + 8 + k0 + kk);
      else                t4 = make_float4(0.f, 0.f, 0.f, 0.f);
      float* dst = &Ws[n * LDP + kk];
      dst[0] = t4.x; dst[1] = t4.y; dst[2] = t4.z; dst[3] = t4.w;
    }
    __syncthreads();
#pragma unroll 4
    for (int k = 0; k < KC; ++k) {
      float a[4], w[10];
#pragma unroll
      for (int mi = 0; mi < 4; ++mi) a[mi] = As[(ty * 4 + mi) * LDP + k];
#pragma unroll
      for (int ni = 0; ni < 10; ++ni) w[ni] = Ws[(tx * 10 + ni) * LDP + k];
#pragma unroll
      for (int mi = 0; mi < 4; ++mi)
#pragma unroll
        for (int ni = 0; ni < 10; ++ni) acc[mi][ni] += a[mi] * w[ni];
    }
    __syncthreads();
  }

  // epilogue: add biases, store
  const float wkb = wsc[0];
#pragma unroll
  for (int ni = 0; ni < 10; ++ni) {
    const int n = tx * 10 + ni;
    if (n < 128) {
      const float bias = wq_b[n];
      float4 o;
      o.x = acc[0][ni] + bias;
      o.y = acc[1][ni] + bias;
      o.z = acc[2][ni] + bias;
      o.w = acc[3][ni] + bias;
      *(float4*)(qT + ((size_t)(b * OUTn + n)) * Jn + j0 + ty * 4) = o;
    } else if (n < 144) {
      const int d = n - 128;
      const float bias = wv_b[d];
#pragma unroll
      for (int mi = 0; mi < 4; ++mi)
        vout[((size_t)b * Jn + j0 + ty * 4 + mi) * HDn + d] = acc[mi][ni] + bias;
    } else if (n == 144) {
      float4 o;
      o.x = acc[0][ni] + wkb;
      o.y = acc[1][ni] + wkb;
      o.z = acc[2][ni] + wkb;
      o.w = acc[3][ni] + wkb;
      *(float4*)(ksum + (size_t)b * Jn + j0 + ty * 4) = o;
    }
  }
}

// ---------------- attention: softmax(tanh(q*ksum)) @ v ----------------------
__global__ __launch_bounds__(256) void attn_kernel(
    const float* __restrict__ qT,
    const float* __restrict__ ksum,
    const float* __restrict__ v,
    float* __restrict__ out)
{
  const int bi  = blockIdx.x;          // b*128 + i
  const int b   = bi >> 7;
  const int tid = threadIdx.x;
  const float* qrow = qT + (size_t)bi * Jn;
  const float* ks   = ksum + (size_t)b * Jn;
  const float* vb   = v + (size_t)b * Jn * HDn;

  float Z = 0.f;
  float racc[HDn];
#pragma unroll
  for (int d = 0; d < HDn; ++d) racc[d] = 0.f;

  for (int j = tid; j < Jn; j += 256) {
    const float attnv = qrow[j] * ks[j];
    // tanh(x) = 1 - 2/(e^{2x}+1): stable both directions (inf -> 1, 0 -> -1)
    const float e2x = __expf(attnv + attnv);
    const float t   = 1.f - 2.f / (e2x + 1.f);
    const float p   = __expf(t);      // t in [-1,1]: no max-subtraction needed
    Z += p;
    const float4* vr = (const float4*)(vb + (size_t)j * HDn);
    const float4 v0 = vr[0], v1 = vr[1], v2 = vr[2], v3 = vr[3];
    racc[0]  += p * v0.x; racc[1]  += p * v0.y; racc[2]  += p * v0.z; racc[3]  += p * v0.w;
    racc[4]  += p * v1.x; racc[5]  += p * v1.y; racc[6]  += p * v1.z; racc[7]  += p * v1.w;
    racc[8]  += p * v2.x; racc[9]  += p * v2.y; racc[10] += p * v2.z; racc[11] += p * v2.w;
    racc[12] += p * v3.x; racc[13] += p * v3.y; racc[14] += p * v3.z; racc[15] += p * v3.w;
  }
  // wave64 butterfly reduce
#pragma unroll
  for (int off = 32; off > 0; off >>= 1) {
    Z += __shfl_down(Z, off);
#pragma unroll
    for (int d = 0; d < HDn; ++d) racc[d] += __shfl_down(racc[d], off);
  }
  __shared__ float red[4][HDn + 1];
  const int wv = tid >> 6;
  if ((tid & 63) == 0) {
    red[wv][0] = Z;
#pragma unroll
    for (int d = 0; d < HDn; ++d) red[wv][1 + d] = racc[d];
  }
  __syncthreads();
  if (tid < HDn + 1) {
    red[0][tid] = red[0][tid] + red[1][tid] + red[2][tid] + red[3][tid];
  }
  __syncthreads();
  if (tid < HDn) {
    out[(size_t)bi * HDn + tid] = red[0][1 + tid] / red[0][0];
  }
}

// ---------------------------------------------------------------------------
extern "C" void kernel_launch(void* const* d_in, const int* in_sizes, int n_in,
                              void* d_out, int out_size, void* d_ws, size_t ws_size,
                              hipStream_t stream) {
  const float* vec  = (const float*)d_in[0];
  const float* wq_w = (const float*)d_in[1];
  const float* wq_b = (const float*)d_in[2];
  const float* wk_w = (const float*)d_in[3];
  const float* wk_b = (const float*)d_in[4];
  const float* wv_w = (const float*)d_in[5];
  const float* wv_b = (const float*)d_in[6];

  float* ws   = (float*)d_ws;
  float* qT   = ws + 4096;                            // [B,128,J] fp32 = 16.8 MB
  float* ksum = qT + (size_t)Bn * OUTn * Jn;          // [B,J]
  float* vout = ksum + (size_t)Bn * Jn;               // [B,J,16]
  float* out  = (float*)d_out;

  prep_kernel<<<33, 256, 0, stream>>>(wk_w, wk_b, ws);
  proj_kernel<<<Bn * (Jn / TJ), 256, 0, stream>>>(vec, wq_w, wq_b, wv_w, wv_b,
                                                  ws, qT, ksum, vout);
  attn_kernel<<<Bn * OUTn, 256, 0, stream>>>(qT, ksum, vout, out);
}

// Round 2
// 450.378 us; speedup vs baseline: 2.1068x; 2.1068x over previous
//
#include <hip/hip_runtime.h>
#include <hip/hip_bf16.h>
#include <math.h>

#define Bn   16
#define Jn   2048
#define Hn   2048
#define OUTn 128
#define HDn  16

// proj tiling: block M=64 (j), N=160 (128 q + 16 v + 1 ksum + 15 zero), KC=64
#define KC      64
#define NCHUNK  (Hn / KC)          // 32
#define A_UNITS 512                // 64*64/8 units of 8 bf16 per plane
#define B_UNITS 1280               // 160*64/8 units per plane
#define WPK_CHUNK_BYTES (2 * B_UNITS * 16)   // 40960 B per chunk (hi+lo)

typedef __attribute__((ext_vector_type(8))) short bf16x8_t;
typedef __attribute__((ext_vector_type(4))) float f32x4_t;

typedef __attribute__((address_space(1))) const void gvoid_t;
typedef __attribute__((address_space(3))) void lvoid_t;

__device__ __forceinline__ unsigned short f2bf(float x) {
  unsigned u = __builtin_bit_cast(unsigned, x);
  unsigned r = (u + 0x7fffu + ((u >> 16) & 1u)) >> 16;
  return (unsigned short)r;
}
__device__ __forceinline__ float bf2f(unsigned short h) {
  unsigned u = ((unsigned)h) << 16;
  return __builtin_bit_cast(float, u);
}

// -------- prep1: wksum[c] = sum_h wk_w[h,c] (atomic partials); ws[0]=sum(wk_b)
__global__ __launch_bounds__(256) void prep1_kernel(const float* __restrict__ wk_w,
                                                    const float* __restrict__ wk_b,
                                                    float* __restrict__ ws) {
  const int blk = blockIdx.x;
  const int tid = threadIdx.x;
  if (blk < 256) {
    const int h0 = blk * 8;
    for (int c = tid; c < Hn; c += 256) {
      float s = 0.f;
#pragma unroll
      for (int h = 0; h < 8; ++h) s += wk_w[(size_t)(h0 + h) * Hn + c];
      atomicAdd(&ws[8 + c], s);
    }
  } else {
    __shared__ float red[256];
    float s = 0.f;
    for (int h = tid; h < Hn; h += 256) s += wk_b[h];
    red[tid] = s;
    __syncthreads();
    for (int off = 128; off > 0; off >>= 1) {
      if (tid < off) red[tid] += red[tid + off];
      __syncthreads();
    }
    if (tid == 0) ws[0] = red[0];
  }
}

// -------- prep2: pack weights into split-bf16, MFMA-tile-linear stream ------
// Row map: n<128 -> wq_w[n], n<144 -> wv_w[n-128], n==144 -> wksum, else 0.
// Unit u (per chunk, per plane) = (kblk*10 + ntile)*64 + g*16 + n16,
// source k = chunk*64 + kblk*32 + g*8 (8 consecutive fp32).
__global__ __launch_bounds__(256) void prep2_kernel(const float* __restrict__ wq_w,
                                                    const float* __restrict__ wv_w,
                                                    const float* __restrict__ wsc,
                                                    uint4* __restrict__ wpk) {
  const int id = blockIdx.x * 256 + threadIdx.x;     // 0 .. 40960
  const int chunk = id / B_UNITS;
  const int u     = id % B_UNITS;
  const int kblk  = u / 640;
  const int u2    = u % 640;
  const int nt    = u2 >> 6;
  const int g     = (u2 >> 4) & 3;
  const int n16   = u2 & 15;
  const int n     = nt * 16 + n16;
  const int k     = chunk * KC + kblk * 32 + g * 8;

  float x[8];
  if (n < OUTn) {
    const float* s = wq_w + (size_t)n * Hn + k;
#pragma unroll
    for (int i = 0; i < 8; ++i) x[i] = s[i];
  } else if (n < OUTn + HDn) {
    const float* s = wv_w + (size_t)(n - OUTn) * Hn + k;
#pragma unroll
    for (int i = 0; i < 8; ++i) x[i] = s[i];
  } else if (n == OUTn + HDn) {
    const float* s = wsc + 8 + k;
#pragma unroll
    for (int i = 0; i < 8; ++i) x[i] = s[i];
  } else {
#pragma unroll
    for (int i = 0; i < 8; ++i) x[i] = 0.f;
  }

  unsigned short hi[8], lo[8];
#pragma unroll
  for (int i = 0; i < 8; ++i) {
    hi[i] = f2bf(x[i]);
    lo[i] = f2bf(x[i] - bf2f(hi[i]));
  }
  uint4 uh, ul;
  uh.x = (unsigned)hi[0] | ((unsigned)hi[1] << 16);
  uh.y = (unsigned)hi[2] | ((unsigned)hi[3] << 16);
  uh.z = (unsigned)hi[4] | ((unsigned)hi[5] << 16);
  uh.w = (unsigned)hi[6] | ((unsigned)hi[7] << 16);
  ul.x = (unsigned)lo[0] | ((unsigned)lo[1] << 16);
  ul.y = (unsigned)lo[2] | ((unsigned)lo[3] << 16);
  ul.z = (unsigned)lo[4] | ((unsigned)lo[5] << 16);
  ul.w = (unsigned)lo[6] | ((unsigned)lo[7] << 16);
  wpk[(size_t)(chunk * 2 + 0) * B_UNITS + u] = uh;
  wpk[(size_t)(chunk * 2 + 1) * B_UNITS + u] = ul;
}

// -------- proj: split-bf16 MFMA GEMM, fused q/v/ksum --------------------------
__global__ __launch_bounds__(256, 2) void proj_kernel(
    const float* __restrict__ vec,
    const float* __restrict__ wq_b,
    const float* __restrict__ wv_b,
    const float* __restrict__ wsc,     // ws[0] = wkb sum
    const uint4* __restrict__ wpk,     // packed split-bf16 weights
    float* __restrict__ qT,            // [B,128,J]
    float* __restrict__ ksum,          // [B,J]
    float* __restrict__ vout)          // [B,J,16]
{
  __shared__ uint4 As[2 * A_UNITS];    // hi then lo, 16 KB
  __shared__ uint4 Bs[2 * B_UNITS];    // hi then lo, 40 KB

  const int tid  = threadIdx.x;
  const int lane = tid & 63;
  const int w    = tid >> 6;           // wave 0..3
  const int wm   = w >> 1;             // wave M half (0/1): rows wm*32..+31
  const int wn   = w & 1;              // wave N half: ntiles wn*5..+4
  const int b    = blockIdx.x >> 5;
  const int j0   = (blockIdx.x & 31) * 64;

  const float* vecb = vec + (size_t)b * Jn * Hn;
  const bf16x8_t* As8 = (const bf16x8_t*)As;
  const bf16x8_t* Bs8 = (const bf16x8_t*)Bs;

  f32x4_t acc[2][5];
#pragma unroll
  for (int mi = 0; mi < 2; ++mi)
#pragma unroll
    for (int ni = 0; ni < 5; ++ni) acc[mi][ni] = (f32x4_t){0.f, 0.f, 0.f, 0.f};

  for (int chunk = 0; chunk < NCHUNK; ++chunk) {
    const int k0 = chunk * KC;
    // ---- stage A: 2 units/thread, each = 8 consecutive fp32 -> hi+lo bf16x8
#pragma unroll
    for (int rep = 0; rep < 2; ++rep) {
      const int u    = tid + rep * 256;       // 0..511
      const int kblk = u >> 8;
      const int mt   = (u >> 6) & 3;
      const int g    = (u >> 4) & 3;
      const int m    = u & 15;
      const float* src = vecb + (size_t)(j0 + mt * 16 + m) * Hn + k0 + kblk * 32 + g * 8;
      const float4 a0 = *(const float4*)src;
      const float4 a1 = *(const float4*)(src + 4);
      float x[8] = {a0.x, a0.y, a0.z, a0.w, a1.x, a1.y, a1.z, a1.w};
      unsigned short hi[8], lo[8];
#pragma unroll
      for (int i = 0; i < 8; ++i) {
        hi[i] = f2bf(x[i]);
        lo[i] = f2bf(x[i] - bf2f(hi[i]));
      }
      uint4 uh, ul;
      uh.x = (unsigned)hi[0] | ((unsigned)hi[1] << 16);
      uh.y = (unsigned)hi[2] | ((unsigned)hi[3] << 16);
      uh.z = (unsigned)hi[4] | ((unsigned)hi[5] << 16);
      uh.w = (unsigned)hi[6] | ((unsigned)hi[7] << 16);
      ul.x = (unsigned)lo[0] | ((unsigned)lo[1] << 16);
      ul.y = (unsigned)lo[2] | ((unsigned)lo[3] << 16);
      ul.z = (unsigned)lo[4] | ((unsigned)lo[5] << 16);
      ul.w = (unsigned)lo[6] | ((unsigned)lo[7] << 16);
      As[u]           = uh;
      As[A_UNITS + u] = ul;
    }
    // ---- stage B: async global->LDS, 16B/lane, pre-packed linear stream
    {
      const char* gbase = (const char*)wpk + (size_t)chunk * WPK_CHUNK_BYTES + (size_t)lane * 16;
#pragma unroll
      for (int i = 0; i < 10; ++i) {
        const int q = w + i * 4;               // 0..39 wave-instrs of 1 KB
        __builtin_amdgcn_global_load_lds((gvoid_t*)(gbase + q * 1024),
                                         (lvoid_t*)&Bs[q * 64], 16, 0, 0);
      }
    }
    __syncthreads();

#pragma unroll
    for (int kblk = 0; kblk < 2; ++kblk) {
      bf16x8_t bh[5], bl[5];
#pragma unroll
      for (int ni = 0; ni < 5; ++ni) {
        const int idx = (kblk * 10 + wn * 5 + ni) * 64 + lane;
        bh[ni] = Bs8[idx];
        bl[ni] = Bs8[B_UNITS + idx];
      }
#pragma unroll
      for (int mi = 0; mi < 2; ++mi) {
        const int aidx = (kblk * 4 + wm * 2 + mi) * 64 + lane;
        const bf16x8_t ah = As8[aidx];
        const bf16x8_t al = As8[A_UNITS + aidx];
#pragma unroll
        for (int ni = 0; ni < 5; ++ni) {
          acc[mi][ni] = __builtin_amdgcn_mfma_f32_16x16x32_bf16(ah, bh[ni], acc[mi][ni], 0, 0, 0);
          acc[mi][ni] = __builtin_amdgcn_mfma_f32_16x16x32_bf16(ah, bl[ni], acc[mi][ni], 0, 0, 0);
          acc[mi][ni] = __builtin_amdgcn_mfma_f32_16x16x32_bf16(al, bh[ni], acc[mi][ni], 0, 0, 0);
        }
      }
    }
    __syncthreads();
  }

  // ---- epilogue: C/D layout col=lane&15, row=(lane>>4)*4+reg
  const float wkb = wsc[0];
  const int col16 = lane & 15;
  const int rbase = (lane >> 4) * 4;
#pragma unroll
  for (int mi = 0; mi < 2; ++mi) {
#pragma unroll
    for (int ni = 0; ni < 5; ++ni) {
      const int n  = (wn * 5 + ni) * 16 + col16;
      const int jg = j0 + (wm * 2 + mi) * 16 + rbase;
      const f32x4_t c = acc[mi][ni];
      if (n < OUTn) {
        const float bias = wq_b[n];
        float4 o = {c[0] + bias, c[1] + bias, c[2] + bias, c[3] + bias};
        *(float4*)(qT + ((size_t)(b * OUTn + n)) * Jn + jg) = o;
      } else if (n < OUTn + HDn) {
        const int d = n - OUTn;
        const float bias = wv_b[d];
#pragma unroll
        for (int r = 0; r < 4; ++r)
          vout[((size_t)b * Jn + jg + r) * HDn + d] = c[r] + bias;
      } else if (n == OUTn + HDn) {
#pragma unroll
        for (int r = 0; r < 4; ++r)
          ksum[(size_t)b * Jn + jg + r] = c[r] + wkb;
      }
    }
  }
}

// -------- attn: softmax(tanh(q*ksum)) @ v -----------------------------------
__global__ __launch_bounds__(256) void attn_kernel(
    const float* __restrict__ qT,
    const float* __restrict__ ksum,
    const float* __restrict__ v,
    float* __restrict__ out)
{
  const int bi  = blockIdx.x;          // b*128 + i
  const int b   = bi >> 7;
  const int tid = threadIdx.x;
  const float* qrow = qT + (size_t)bi * Jn;
  const float* ks   = ksum + (size_t)b * Jn;
  const float* vb   = v + (size_t)b * Jn * HDn;

  float Z = 0.f;
  float racc[HDn];
#pragma unroll
  for (int d = 0; d < HDn; ++d) racc[d] = 0.f;

  for (int j = tid; j < Jn; j += 256) {
    const float attnv = qrow[j] * ks[j];
    const float e2x = __expf(attnv + attnv);
    const float t   = 1.f - 2.f / (e2x + 1.f);
    const float p   = __expf(t);
    Z += p;
    const float4* vr = (const float4*)(vb + (size_t)j * HDn);
    const float4 v0 = vr[0], v1 = vr[1], v2 = vr[2], v3 = vr[3];
    racc[0]  += p * v0.x; racc[1]  += p * v0.y; racc[2]  += p * v0.z; racc[3]  += p * v0.w;
    racc[4]  += p * v1.x; racc[5]  += p * v1.y; racc[6]  += p * v1.z; racc[7]  += p * v1.w;
    racc[8]  += p * v2.x; racc[9]  += p * v2.y; racc[10] += p * v2.z; racc[11] += p * v2.w;
    racc[12] += p * v3.x; racc[13] += p * v3.y; racc[14] += p * v3.z; racc[15] += p * v3.w;
  }
#pragma unroll
  for (int off = 32; off > 0; off >>= 1) {
    Z += __shfl_down(Z, off);
#pragma unroll
    for (int d = 0; d < HDn; ++d) racc[d] += __shfl_down(racc[d], off);
  }
  __shared__ float red[4][HDn + 1];
  const int wv = tid >> 6;
  if ((tid & 63) == 0) {
    red[wv][0] = Z;
#pragma unroll
    for (int d = 0; d < HDn; ++d) red[wv][1 + d] = racc[d];
  }
  __syncthreads();
  if (tid < HDn + 1) {
    red[0][tid] = red[0][tid] + red[1][tid] + red[2][tid] + red[3][tid];
  }
  __syncthreads();
  if (tid < HDn) {
    out[(size_t)bi * HDn + tid] = red[0][1 + tid] / red[0][0];
  }
}

// ---------------------------------------------------------------------------
extern "C" void kernel_launch(void* const* d_in, const int* in_sizes, int n_in,
                              void* d_out, int out_size, void* d_ws, size_t ws_size,
                              hipStream_t stream) {
  const float* vec  = (const float*)d_in[0];
  const float* wq_w = (const float*)d_in[1];
  const float* wq_b = (const float*)d_in[2];
  const float* wk_w = (const float*)d_in[3];
  const float* wk_b = (const float*)d_in[4];
  const float* wv_w = (const float*)d_in[5];
  const float* wv_b = (const float*)d_in[6];

  float* ws   = (float*)d_ws;
  uint4* wpk  = (uint4*)(ws + 4096);                       // 1.31 MB packed weights
  float* qT   = ws + 4096 + (NCHUNK * 2 * B_UNITS * 4);    // [B,128,J] fp32
  float* ksum = qT + (size_t)Bn * OUTn * Jn;               // [B,J]
  float* vout = ksum + (size_t)Bn * Jn;                    // [B,J,16]
  float* out  = (float*)d_out;

  hipMemsetAsync(ws, 0, (8 + Hn) * sizeof(float), stream);
  prep1_kernel<<<257, 256, 0, stream>>>(wk_w, wk_b, ws);
  prep2_kernel<<<(NCHUNK * B_UNITS) / 256, 256, 0, stream>>>(wq_w, wv_w, ws, wpk);
  proj_kernel<<<Bn * (Jn / 64), 256, 0, stream>>>(vec, wq_b, wv_b, ws, wpk,
                                                  qT, ksum, vout);
  attn_kernel<<<Bn * OUTn, 256, 0, stream>>>(qT, ksum, vout, out);
}